// Round 11
// baseline (186.817 us; speedup 1.0000x reference)
//
#include <hip/hip_runtime.h>
#include <hip/hip_bf16.h>
#include <stdint.h>
#include <stddef.h>

using bf16 = __hip_bfloat16;
typedef short short8 __attribute__((ext_vector_type(8)));
typedef short short4v __attribute__((ext_vector_type(4)));
typedef short short2v __attribute__((ext_vector_type(2)));
typedef float f32x4 __attribute__((ext_vector_type(4)));
typedef float f32x16 __attribute__((ext_vector_type(16)));
typedef unsigned uintv4 __attribute__((ext_vector_type(4)));

#define MFMA16(A, B, C) __builtin_amdgcn_mfma_f32_16x16x32_bf16(A, B, C, 0, 0, 0)
#define MFMA32(A, B, C) __builtin_amdgcn_mfma_f32_32x32x16_bf16(A, B, C, 0, 0, 0)
#define GLOAD_LDS(g, l) __builtin_amdgcn_global_load_lds( \
    (const __attribute__((address_space(1))) void*)(g),   \
    (__attribute__((address_space(3))) void*)(l), 16, 0, 0)

// Problem constants
constexpr int AN  = 4096;   // sequence length N
constexpr int NH  = 16;     // heads
constexpr int HD  = 64;     // head dim
constexpr int CC  = 1024;   // channels = NH*HD
constexpr int C3  = 3072;   // 3*CC
// Q pre-scale: D^-0.5 * log2(e)  -> softmax runs in exp2 domain
constexpr float QSCALE = 0.125f * 1.4426950408889634f;

// ---- fast f32 -> bf16 (hardware cvt_pk if present, else bias+perm trick) ----
__device__ inline short bf16s(float f) {
    return (short)((__float_as_uint(f) + 0x8000u) >> 16);
}
__device__ inline float bf2f(short s) {
    return __uint_as_float(((unsigned)(unsigned short)s) << 16);
}
__device__ inline bf16 sbf(short s) {
    union { short s; bf16 b; } u;
    u.s = s;
    return u.b;
}
#if __has_builtin(__builtin_amdgcn_cvt_pk_bf16_f32)
typedef __bf16 bf16x2 __attribute__((ext_vector_type(2)));
__device__ inline short2v pk2(float a, float b) {
    bf16x2 r = __builtin_amdgcn_cvt_pk_bf16_f32(a, b);
    return *(short2v*)&r;
}
#else
__device__ inline short2v pk2(float a, float b) {   // 3 inst
    unsigned ua = __float_as_uint(a) + 0x8000u;
    unsigned ub = __float_as_uint(b) + 0x8000u;
    unsigned r  = __builtin_amdgcn_perm(ub, ua, 0x07060302);
    return *(short2v*)&r;
}
#endif
__device__ inline unsigned pk2u(float a, float b) {
    short2v p = pk2(a, b);
    return *(unsigned*)&p;
}
__device__ inline short4v pack4(float a, float b, float c, float d) {
    short2v lo = pk2(a, b), hi = pk2(c, d);
    short4v r;
    r[0] = lo[0]; r[1] = lo[1]; r[2] = hi[0]; r[3] = hi[1];
    return r;
}
// v_permlane32_swap_b32: upper 32 lanes of %0 exchange with lower 32 lanes
// of %1. After: a = [a_lo | b_lo(from lane-32)], b = [a_hi(from lane+32) | b_hi].
__device__ inline void plswap(unsigned &a, unsigned &b) {
    asm("v_permlane32_swap_b32 %0, %1" : "+v"(a), "+v"(b));
}
#if __has_builtin(__builtin_amdgcn_exp2f)
#define FAST_EXP2(x) __builtin_amdgcn_exp2f(x)
#else
#define FAST_EXP2(x) exp2f(x)
#endif

// ---------------------------------------------------------------------------
// Per-wave dtype detect (no extra kernel): every wave reads the same first
// 256 shorts of x; fp32-read-as-bf16 has ~45% wild exponents.
// ---------------------------------------------------------------------------
__device__ inline int detect_mode_inline(const unsigned short* xraw, int lane) {
    int crazy = 0;
    #pragma unroll
    for (int i = 0; i < 4; ++i) {
        const unsigned short u = xraw[lane * 4 + i];
        const int e = (u >> 7) & 0xFF;
        if (e >= 134 || (e != 0 && e <= 110)) ++crazy;
    }
    #pragma unroll
    for (int off = 32; off > 0; off >>= 1)
        crazy += __shfl_down(crazy, off, 64);
    crazy = __shfl(crazy, 0, 64);   // wave-uniform
    return (crazy >= 8) ? 1 : 0;
}

// ---------------------------------------------------------------------------
// One merged cast kernel: x (2048 blocks) | w_qkv (1536) | w_proj (512) |
// bias+mode (1 block). 8 elements/thread. Mode derived per-wave in-kernel.
// ---------------------------------------------------------------------------
__device__ inline void cast8(const void* __restrict__ src,
                             bf16* __restrict__ dst, int i, int m) {
    if (m) {
        const float* s = (const float*)src;
        float4 a = *(const float4*)(s + i);
        float4 b = *(const float4*)(s + i + 4);
        short8 o;
        short2v p0 = pk2(a.x, a.y), p1 = pk2(a.z, a.w);
        short2v p2 = pk2(b.x, b.y), p3 = pk2(b.z, b.w);
        o[0] = p0[0]; o[1] = p0[1]; o[2] = p1[0]; o[3] = p1[1];
        o[4] = p2[0]; o[5] = p2[1]; o[6] = p3[0]; o[7] = p3[1];
        *(short8*)(dst + i) = o;
    } else {
        *(short8*)(dst + i) = *(const short8*)((const short*)src + i);
    }
}

__global__ void cast_all(const void* __restrict__ x, const void* __restrict__ wq,
                         const void* __restrict__ wp, const void* __restrict__ bp,
                         bf16* __restrict__ xb, bf16* __restrict__ wqb,
                         bf16* __restrict__ wpb, float* __restrict__ biasf,
                         int* __restrict__ mode) {
    const int b = blockIdx.x;
    const int tid = threadIdx.x;
    const int m = detect_mode_inline((const unsigned short*)x, tid & 63);
    if (b < 2048) {
        cast8(x, xb, (b * 256 + tid) * 8, m);
    } else if (b < 3584) {
        cast8(wq, wqb, ((b - 2048) * 256 + tid) * 8, m);
    } else if (b < 4096) {
        cast8(wp, wpb, ((b - 3584) * 256 + tid) * 8, m);
    } else {
        #pragma unroll
        for (int i = tid; i < CC; i += 256)
            biasf[i] = m ? ((const float*)bp)[i] : bf2f(((const short*)bp)[i]);
        if (tid == 0) *mode = m;   // for gemm_proj's output dtype
    }
}

// ---------------------------------------------------------------------------
// QKV GEMM: Q cols scaled by QSCALE into qbuf[n][CC]; K cols written to
// fragment-major kPack[h][kvtile][dchunk(8)][row(64)][8]; V cols written to
// fragment-major vPack[h][kvtile][kvchunk(8)][d(64)][8].
// [Round-8 lesson: swapped-operand K epilogue = 188 MB writes; reverted.]
// 128x128 tile, BK=32, grid 24x32 = 768 = 3 blocks/CU exact fill.
// ---------------------------------------------------------------------------
constexpr int BM = 128, BN = 128, BK = 32;

__global__ __launch_bounds__(256, 3) void gemm_qkv(
    const bf16* __restrict__ A, const bf16* __restrict__ Bw,
    bf16* __restrict__ qOut, bf16* __restrict__ kOut, bf16* __restrict__ vOut)
{
    __shared__ bf16 As[BM * BK];
    __shared__ bf16 Bs[BN * BK];

    const int tid  = threadIdx.x;
    const int wave = tid >> 6;
    const int lane = tid & 63;
    const int quad = lane >> 4;
    const int l16  = lane & 15;
    const int wr   = wave >> 1;
    const int wc   = wave & 1;
    const int m0   = blockIdx.y * BM;
    const int o0   = blockIdx.x * BN;

    const int srow = lane >> 2;
    const int scol = (lane & 3) * 8;

    f32x4 acc[4][4] = {};

    for (int k0 = 0; k0 < CC; k0 += BK) {
        __syncthreads();
        #pragma unroll
        for (int c = 0; c < 2; ++c) {
            const int rbase = wave * 32 + c * 16;
            GLOAD_LDS(A + (size_t)(m0 + rbase + srow) * CC + k0 + scol, &As[rbase * BK]);
            GLOAD_LDS(Bw + (size_t)(o0 + rbase + srow) * CC + k0 + scol, &Bs[rbase * BK]);
        }
        __syncthreads();

        short8 af[4], bfr[4];
        #pragma unroll
        for (int i = 0; i < 4; ++i)
            af[i] = *(const short8*)&As[(wr * 64 + i * 16 + l16) * BK + quad * 8];
        #pragma unroll
        for (int j = 0; j < 4; ++j)
            bfr[j] = *(const short8*)&Bs[(wc * 64 + j * 16 + l16) * BK + quad * 8];
        #pragma unroll
        for (int i = 0; i < 4; ++i)
            #pragma unroll
            for (int j = 0; j < 4; ++j)
                acc[i][j] = MFMA16(af[i], bfr[j], acc[i][j]);
    }

    // epilogue: C/D layout col=l16, row=quad*4+reg
    if (o0 >= 2 * CC) {   // V block -> vPack[h][tile][kvchunk][d][8]
        #pragma unroll
        for (int j = 0; j < 4; ++j) {
            const int dcol = o0 - 2 * CC + wc * 64 + j * 16 + l16;
            const int hV = dcol >> 6, dV = dcol & 63;
            #pragma unroll
            for (int i = 0; i < 4; ++i) {
                const int kv0 = m0 + wr * 64 + i * 16 + quad * 4;
                const size_t addr = (size_t)hV * 64 * AN + (size_t)(kv0 >> 6) * 4096
                                  + (size_t)((kv0 >> 3) & 7) * 512 + dV * 8 + (kv0 & 7);
                *(short4v*)&vOut[addr] =
                    pack4(acc[i][j][0], acc[i][j][1], acc[i][j][2], acc[i][j][3]);
            }
        }
        return;
    }
    if (o0 >= CC) {       // K block -> kPack[h][tile][dchunk][row][8]
        #pragma unroll
        for (int j = 0; j < 4; ++j) {
            const int dcol = o0 - CC + wc * 64 + j * 16 + l16;
            const int hK = dcol >> 6, dc = (dcol >> 3) & 7, de = dcol & 7;
            #pragma unroll
            for (int i = 0; i < 4; ++i) {
                const int kv0 = m0 + wr * 64 + i * 16 + quad * 4;
                const size_t addr = (size_t)hK * 64 * AN + (size_t)(kv0 >> 6) * 4096
                                  + (size_t)dc * 512 + (size_t)(kv0 & 63) * 8 + de;
                #pragma unroll
                for (int r = 0; r < 4; ++r)
                    kOut[addr + r * 8] = sbf(bf16s(acc[i][j][r]));
            }
        }
        return;
    }
    // Q block -> qbuf[n][CC], scaled
    #pragma unroll
    for (int j = 0; j < 4; ++j) {
        const int col = o0 + wc * 64 + j * 16 + l16;
        #pragma unroll
        for (int i = 0; i < 4; ++i) {
            const int row = m0 + wr * 64 + i * 16 + quad * 4;
            #pragma unroll
            for (int r = 0; r < 2; ++r) {
                short2v p = pk2(acc[i][j][2 * r] * QSCALE, acc[i][j][2 * r + 1] * QSCALE);
                qOut[(size_t)(row + 2 * r) * CC + col]     = sbf(p[0]);
                qOut[(size_t)(row + 2 * r + 1) * CC + col] = sbf(p[1]);
            }
        }
    }
}

// ---------------------------------------------------------------------------
// Proj GEMM: out[m][o] = sum_c attn[m][c]*wp[o][c] + bias[o].
// 128x64 tile -> grid 16x32 = 512 = 2 blocks/CU exact fill.
// ---------------------------------------------------------------------------
constexpr int PM = 128, PN = 64, PK = 32;

__global__ __launch_bounds__(256, 2) void gemm_proj(
    const bf16* __restrict__ A, const bf16* __restrict__ Bw,
    const float* __restrict__ bias, void* __restrict__ Cout,
    const int* __restrict__ mode)
{
    __shared__ bf16 As[PM * PK];   // 8 KB
    __shared__ bf16 Bs[PN * PK];   // 4 KB

    const int tid  = threadIdx.x;
    const int wave = tid >> 6;
    const int lane = tid & 63;
    const int quad = lane >> 4;
    const int l16  = lane & 15;
    const int wr   = wave >> 1;
    const int wc   = wave & 1;
    const int m0   = blockIdx.y * PM;
    const int o0   = blockIdx.x * PN;
    const bool f32out = (*mode != 0);

    const int srow = lane >> 2;
    const int scol = (lane & 3) * 8;

    f32x4 acc[4][2] = {};

    for (int k0 = 0; k0 < CC; k0 += PK) {
        __syncthreads();
        #pragma unroll
        for (int c = 0; c < 2; ++c) {
            const int rbase = wave * 32 + c * 16;
            GLOAD_LDS(A + (size_t)(m0 + rbase + srow) * CC + k0 + scol, &As[rbase * PK]);
        }
        {
            const int rbase = wave * 16;
            GLOAD_LDS(Bw + (size_t)(o0 + rbase + srow) * CC + k0 + scol, &Bs[rbase * PK]);
        }
        __syncthreads();

        short8 af[4], bfr[2];
        #pragma unroll
        for (int i = 0; i < 4; ++i)
            af[i] = *(const short8*)&As[(wr * 64 + i * 16 + l16) * PK + quad * 8];
        #pragma unroll
        for (int j = 0; j < 2; ++j)
            bfr[j] = *(const short8*)&Bs[(wc * 32 + j * 16 + l16) * PK + quad * 8];
        #pragma unroll
        for (int i = 0; i < 4; ++i)
            #pragma unroll
            for (int j = 0; j < 2; ++j)
                acc[i][j] = MFMA16(af[i], bfr[j], acc[i][j]);
    }

    #pragma unroll
    for (int j = 0; j < 2; ++j) {
        const int col = o0 + wc * 32 + j * 16 + l16;
        const float bv = bias[col];
        #pragma unroll
        for (int i = 0; i < 4; ++i) {
            const int row = m0 + wr * 64 + i * 16 + quad * 4;
            if (f32out) {
                #pragma unroll
                for (int r = 0; r < 4; ++r)
                    ((float*)Cout)[(size_t)(row + r) * CC + col] = acc[i][j][r] + bv;
            } else {
                #pragma unroll
                for (int r = 0; r < 2; ++r) {
                    short2v p = pk2(acc[i][j][2 * r] + bv, acc[i][j][2 * r + 1] + bv);
                    ((bf16*)Cout)[(size_t)(row + 2 * r) * CC + col]     = sbf(p[0]);
                    ((bf16*)Cout)[(size_t)(row + 2 * r + 1) * CC + col] = sbf(p[1]);
                }
            }
        }
    }
}

// ---------------------------------------------------------------------------
// Causal flash attention v17: attn14's wave program (164 total regs -> HW
// permits 3 waves/SIMD) with a 4096-wave grid so the grid no longer caps
// residency at 2/SIMD.  [Round-10 insight: occupancy = min(grid-waves/1024,
// 512/total-regs) per SIMD; attn14 was grid-capped, not register-capped.]
//  - 1024 blocks = (h, tile) with tile = 63 - (bid>>4): LARGEST-FIRST
//    dispatch so big tiles launch first and small ones backfill the tail
//    (LPT scheduling; no (t,63-t) pairing needed).
//  - 4 waves = (rowhalf rh, kv-half s); wave s runs kv-half of [0, tile+1).
//  - in-block combine: s=1 parks acc/l in LDS (16.5 KB), one barrier, s=0
//    merges, normalizes, writes final O. One barrier total.
// Per-wave inner program byte-identical to attn8/14: reg-direct K/V frags,
// V at iter top, K prefetch after S, lsum ones-MFMA, fixed-max exp2
// softmax, permlane P-frag build.
// ---------------------------------------------------------------------------
__global__ __launch_bounds__(256, 2) void attn17(
    const bf16* __restrict__ qbuf, const bf16* __restrict__ kP,
    const bf16* __restrict__ vP, bf16* __restrict__ outO)
{
    __shared__ float ldsO[2][32][64];   // [rh][reg][lane] 16 KB
    __shared__ float ldsL[2][64];       // 512 B

    const int tid  = threadIdx.x;
    const int w    = tid >> 6;        // 0..3
    const int rh   = w & 1;           // q row-half
    const int s    = w >> 1;          // kv half
    const int lane = tid & 63;
    const int l31  = lane & 31;
    const int hh   = lane >> 5;       // K-half of the 32x32x16 fragment
    const int bid  = blockIdx.x;
    const int h    = bid & 15;
    const int tile = 63 - (bid >> 4); // largest-first

    short8 ones8;
    #pragma unroll
    for (int i = 0; i < 8; ++i) ones8[i] = (short)0x3F80;

    const int nIt  = tile + 1;
    const int mid  = (nIt + 1) >> 1;
    const int i0   = s ? mid : 0;
    const int iHi  = s ? nIt : mid;
    const int qw   = tile * 64 + rh * 32;
    const int q    = qw + l31;

    // Q fragments: B-operand Q[k=hd][col=q]; hd = ki*16 + hh*8 + j
    short8 qf[4];
    {
        const bf16* qp = qbuf + (size_t)q * CC + h * HD + hh * 8;
        #pragma unroll
        for (int ki = 0; ki < 4; ++ki)
            qf[ki] = *(const short8*)(qp + ki * 16);
    }

    f32x16 acc_l = {};       // lsum (rows identical per lane)
    f32x16 acc_o[2] = {};    // O^T: row d = dt*32 + (r&3)+8*(r>>2)+4*hh, col q=l31

    if (i0 < iHi) {
        const bf16* kb = kP + (size_t)h * 64 * AN + (size_t)i0 * 4096;
        const bf16* vb = vP + (size_t)h * 64 * AN + (size_t)i0 * 4096;
        const bool hasdiag = (iHi == nIt);

        // prologue: K(i0) direct to registers
        short8 kf[8];
        #pragma unroll
        for (int kt = 0; kt < 2; ++kt)
            #pragma unroll
            for (int ki = 0; ki < 4; ++ki)
                kf[kt * 4 + ki] = *(const short8*)
                    (kb + (2 * ki + hh) * 512 + kt * 256 + l31 * 8);
        kb += 4096;

        for (int it = i0; it < iHi; ++it) {
            // ---- issue V(it) loads (consumed in PV, after S+softmax) ----
            short8 vf[8];
            #pragma unroll
            for (int kk = 0; kk < 4; ++kk)
                #pragma unroll
                for (int dt2 = 0; dt2 < 2; ++dt2)
                    vf[kk * 2 + dt2] = *(const short8*)
                        (vb + (2 * kk + hh) * 512 + dt2 * 256 + l31 * 8);
            vb += 4096;

            // ---- S^T = K.Q^T, two 32x32 kv-subtiles ----
            f32x16 st[2];
            __builtin_amdgcn_s_setprio(1);
            #pragma unroll
            for (int kt = 0; kt < 2; ++kt) {
                f32x16 a = {};
                #pragma unroll
                for (int ki = 0; ki < 4; ++ki)
                    a = MFMA32(kf[kt * 4 + ki], qf[ki], a);
                st[kt] = a;
            }
            __builtin_amdgcn_s_setprio(0);

            // ---- issue K(it+1) into kf (regs dead after S) ----
            if (it + 1 < iHi) {
                #pragma unroll
                for (int kt = 0; kt < 2; ++kt)
                    #pragma unroll
                    for (int ki = 0; ki < 4; ++ki)
                        kf[kt * 4 + ki] = *(const short8*)
                            (kb + (2 * ki + hh) * 512 + kt * 256 + l31 * 8);
                kb += 4096;
            }

            // ---- fixed-max softmax: P = exp2(s), mask on diag tile ----
            if (hasdiag && it == iHi - 1) {
                const int kv0 = it * 64;
                #pragma unroll
                for (int kt = 0; kt < 2; ++kt)
                    #pragma unroll
                    for (int r = 0; r < 16; ++r) {
                        const int kv = kv0 + kt * 32 + (r & 3) + 8 * (r >> 2) + 4 * hh;
                        st[kt][r] = (kv <= q) ? FAST_EXP2(st[kt][r]) : 0.0f;
                    }
            } else {
                #pragma unroll
                for (int kt = 0; kt < 2; ++kt)
                    #pragma unroll
                    for (int r = 0; r < 16; ++r)
                        st[kt][r] = FAST_EXP2(st[kt][r]);
            }

            // ---- P B-frags (cvt_pk + permlane32_swap), lsum-MFMA + PV ----
            #pragma unroll
            for (int kt = 0; kt < 2; ++kt)
                #pragma unroll
                for (int kc = 0; kc < 2; ++kc) {
                    unsigned a0 = pk2u(st[kt][kc * 8 + 0], st[kt][kc * 8 + 1]);
                    unsigned a1 = pk2u(st[kt][kc * 8 + 2], st[kt][kc * 8 + 3]);
                    unsigned c0 = pk2u(st[kt][kc * 8 + 4], st[kt][kc * 8 + 5]);
                    unsigned c1 = pk2u(st[kt][kc * 8 + 6], st[kt][kc * 8 + 7]);
                    plswap(a0, c0);
                    plswap(a1, c1);
                    uintv4 fu;
                    fu[0] = a0; fu[1] = a1; fu[2] = c0; fu[3] = c1;
                    const short8 frag = *(const short8*)&fu;

                    __builtin_amdgcn_s_setprio(1);
                    acc_l = MFMA32(ones8, frag, acc_l);
                    #pragma unroll
                    for (int dt2 = 0; dt2 < 2; ++dt2)
                        acc_o[dt2] = MFMA32(vf[(kt * 2 + kc) * 2 + dt2],
                                            frag, acc_o[dt2]);
                    __builtin_amdgcn_s_setprio(0);
                }
        }
    }

    // ---- in-block combine: s=1 parks partials, s=0 merges & writes ----
    if (s == 1) {
        #pragma unroll
        for (int dt2 = 0; dt2 < 2; ++dt2)
            #pragma unroll
            for (int r = 0; r < 16; ++r)
                ldsO[rh][dt2 * 16 + r][lane] = acc_o[dt2][r];
        ldsL[rh][lane] = acc_l[0];
    }
    __syncthreads();
    if (s == 0) {
        const float L = acc_l[0] + ldsL[rh][lane];
        const float invL = (L > 0.f) ? 1.f / L : 0.f;
        const size_t base = (size_t)q * CC + h * HD;
        #pragma unroll
        for (int dt2 = 0; dt2 < 2; ++dt2)
            #pragma unroll
            for (int g = 0; g < 4; ++g) {
                const int d0 = dt2 * 32 + g * 8 + 4 * hh;
                float o0 = (acc_o[dt2][4 * g + 0] + ldsO[rh][dt2 * 16 + 4 * g + 0][lane]) * invL;
                float o1 = (acc_o[dt2][4 * g + 1] + ldsO[rh][dt2 * 16 + 4 * g + 1][lane]) * invL;
                float o2 = (acc_o[dt2][4 * g + 2] + ldsO[rh][dt2 * 16 + 4 * g + 2][lane]) * invL;
                float o3 = (acc_o[dt2][4 * g + 3] + ldsO[rh][dt2 * 16 + 4 * g + 3][lane]) * invL;
                *(short4v*)&outO[base + d0] = pack4(o0, o1, o2, o3);
            }
    }
}

// ---------------------------------------------------------------------------
extern "C" void kernel_launch(void* const* d_in, const int* in_sizes, int n_in,
                              void* d_out, int out_size, void* d_ws, size_t ws_size,
                              hipStream_t stream) {
    char* ws = (char*)d_ws;
    bf16*   qbuf     = (bf16*)(ws);                    //  8 MiB [4096][1024]
    bf16*   kPack    = (bf16*)(ws + 8388608);          //  8 MiB frag-major K
    bf16*   vPack    = (bf16*)(ws + 16777216);         //  8 MiB frag-major V
    bf16*   attn_out = (bf16*)(ws + 25165824);         //  8 MiB [4096][1024]
    bf16*   xb       = (bf16*)(ws + 33554432);         //  8 MiB
    bf16*   wqkvb    = (bf16*)(ws + 41943040);         //  6 MiB
    bf16*   wprojb   = (bf16*)(ws + 48234496);         //  2 MiB
    float*  biasf    = (float*)(ws + 50331648);        //  4 KiB
    int*    mode     = (int*)(ws + 50335744);

    cast_all<<<dim3(4097), 256, 0, stream>>>(
        d_in[0], d_in[1], d_in[2], d_in[3], xb, wqkvb, wprojb, biasf, mode);

    // QKV projection: Q scaled -> qbuf; K -> kPack; V -> vPack (frag-major)
    gemm_qkv<<<dim3(C3 / BN, AN / BM), 256, 0, stream>>>(
        xb, wqkvb, qbuf, kPack, vPack);
    // causal flash attention: 1024 blocks largest-first, in-block combine
    attn17<<<dim3(64 * NH), 256, 0, stream>>>(qbuf, kPack, vPack, attn_out);
    // output projection + bias
    gemm_proj<<<dim3(CC / PN, AN / PM), 256, 0, stream>>>(
        attn_out, wprojb, biasf, d_out, mode);
}

// Round 12
// 185.473 us; speedup vs baseline: 1.0072x; 1.0072x over previous
//
#include <hip/hip_runtime.h>
#include <hip/hip_bf16.h>
#include <stdint.h>
#include <stddef.h>

using bf16 = __hip_bfloat16;
typedef short short8 __attribute__((ext_vector_type(8)));
typedef short short4v __attribute__((ext_vector_type(4)));
typedef short short2v __attribute__((ext_vector_type(2)));
typedef float f32x4 __attribute__((ext_vector_type(4)));
typedef float f32x16 __attribute__((ext_vector_type(16)));
typedef unsigned uintv4 __attribute__((ext_vector_type(4)));

#define MFMA16(A, B, C) __builtin_amdgcn_mfma_f32_16x16x32_bf16(A, B, C, 0, 0, 0)
#define MFMA32(A, B, C) __builtin_amdgcn_mfma_f32_32x32x16_bf16(A, B, C, 0, 0, 0)
#define GLOAD_LDS(g, l) __builtin_amdgcn_global_load_lds( \
    (const __attribute__((address_space(1))) void*)(g),   \
    (__attribute__((address_space(3))) void*)(l), 16, 0, 0)

// Problem constants
constexpr int AN  = 4096;   // sequence length N
constexpr int NH  = 16;     // heads
constexpr int HD  = 64;     // head dim
constexpr int CC  = 1024;   // channels = NH*HD
constexpr int C3  = 3072;   // 3*CC
// Q pre-scale: D^-0.5 * log2(e)  -> softmax runs in exp2 domain
constexpr float QSCALE = 0.125f * 1.4426950408889634f;

// ---- fast f32 -> bf16 (hardware cvt_pk if present, else bias+perm trick) ----
__device__ inline short bf16s(float f) {
    return (short)((__float_as_uint(f) + 0x8000u) >> 16);
}
__device__ inline float bf2f(short s) {
    return __uint_as_float(((unsigned)(unsigned short)s) << 16);
}
__device__ inline bf16 sbf(short s) {
    union { short s; bf16 b; } u;
    u.s = s;
    return u.b;
}
#if __has_builtin(__builtin_amdgcn_cvt_pk_bf16_f32)
typedef __bf16 bf16x2 __attribute__((ext_vector_type(2)));
__device__ inline short2v pk2(float a, float b) {
    bf16x2 r = __builtin_amdgcn_cvt_pk_bf16_f32(a, b);
    return *(short2v*)&r;
}
#else
__device__ inline short2v pk2(float a, float b) {   // 3 inst
    unsigned ua = __float_as_uint(a) + 0x8000u;
    unsigned ub = __float_as_uint(b) + 0x8000u;
    unsigned r  = __builtin_amdgcn_perm(ub, ua, 0x07060302);
    return *(short2v*)&r;
}
#endif
__device__ inline unsigned pk2u(float a, float b) {
    short2v p = pk2(a, b);
    return *(unsigned*)&p;
}
__device__ inline short4v pack4(float a, float b, float c, float d) {
    short2v lo = pk2(a, b), hi = pk2(c, d);
    short4v r;
    r[0] = lo[0]; r[1] = lo[1]; r[2] = hi[0]; r[3] = hi[1];
    return r;
}
// v_permlane32_swap_b32: upper 32 lanes of %0 exchange with lower 32 lanes
// of %1. After: a = [a_lo | b_lo(from lane-32)], b = [a_hi(from lane+32) | b_hi].
__device__ inline void plswap(unsigned &a, unsigned &b) {
    asm("v_permlane32_swap_b32 %0, %1" : "+v"(a), "+v"(b));
}
#if __has_builtin(__builtin_amdgcn_exp2f)
#define FAST_EXP2(x) __builtin_amdgcn_exp2f(x)
#else
#define FAST_EXP2(x) exp2f(x)
#endif

// ---------------------------------------------------------------------------
// Per-wave dtype detect (no extra kernel): every wave reads the same first
// 256 shorts of x; fp32-read-as-bf16 has ~45% wild exponents.
// ---------------------------------------------------------------------------
__device__ inline int detect_mode_inline(const unsigned short* xraw, int lane) {
    int crazy = 0;
    #pragma unroll
    for (int i = 0; i < 4; ++i) {
        const unsigned short u = xraw[lane * 4 + i];
        const int e = (u >> 7) & 0xFF;
        if (e >= 134 || (e != 0 && e <= 110)) ++crazy;
    }
    #pragma unroll
    for (int off = 32; off > 0; off >>= 1)
        crazy += __shfl_down(crazy, off, 64);
    crazy = __shfl(crazy, 0, 64);   // wave-uniform
    return (crazy >= 8) ? 1 : 0;
}

// ---------------------------------------------------------------------------
// One merged cast kernel: x (2048 blocks) | w_qkv (1536) | w_proj (512) |
// bias+mode (1 block). 8 elements/thread. Mode derived per-wave in-kernel.
// ---------------------------------------------------------------------------
__device__ inline void cast8(const void* __restrict__ src,
                             bf16* __restrict__ dst, int i, int m) {
    if (m) {
        const float* s = (const float*)src;
        float4 a = *(const float4*)(s + i);
        float4 b = *(const float4*)(s + i + 4);
        short8 o;
        short2v p0 = pk2(a.x, a.y), p1 = pk2(a.z, a.w);
        short2v p2 = pk2(b.x, b.y), p3 = pk2(b.z, b.w);
        o[0] = p0[0]; o[1] = p0[1]; o[2] = p1[0]; o[3] = p1[1];
        o[4] = p2[0]; o[5] = p2[1]; o[6] = p3[0]; o[7] = p3[1];
        *(short8*)(dst + i) = o;
    } else {
        *(short8*)(dst + i) = *(const short8*)((const short*)src + i);
    }
}

__global__ void cast_all(const void* __restrict__ x, const void* __restrict__ wq,
                         const void* __restrict__ wp, const void* __restrict__ bp,
                         bf16* __restrict__ xb, bf16* __restrict__ wqb,
                         bf16* __restrict__ wpb, float* __restrict__ biasf,
                         int* __restrict__ mode) {
    const int b = blockIdx.x;
    const int tid = threadIdx.x;
    const int m = detect_mode_inline((const unsigned short*)x, tid & 63);
    if (b < 2048) {
        cast8(x, xb, (b * 256 + tid) * 8, m);
    } else if (b < 3584) {
        cast8(wq, wqb, ((b - 2048) * 256 + tid) * 8, m);
    } else if (b < 4096) {
        cast8(wp, wpb, ((b - 3584) * 256 + tid) * 8, m);
    } else {
        #pragma unroll
        for (int i = tid; i < CC; i += 256)
            biasf[i] = m ? ((const float*)bp)[i] : bf2f(((const short*)bp)[i]);
        if (tid == 0) *mode = m;   // for gemm_proj's output dtype
    }
}

// ---------------------------------------------------------------------------
// QKV GEMM: Q cols scaled by QSCALE into qbuf[n][CC]; K cols written to
// fragment-major kPack[h][kvtile][dchunk(8)][row(64)][8]; V cols written to
// fragment-major vPack[h][kvtile][kvchunk(8)][d(64)][8].
// [Round-8 lesson: swapped-operand K epilogue = 188 MB writes; reverted.]
// 128x128 tile, BK=32, grid 24x32 = 768 = 3 blocks/CU exact fill.
// ---------------------------------------------------------------------------
constexpr int BM = 128, BN = 128, BK = 32;

__global__ __launch_bounds__(256, 3) void gemm_qkv(
    const bf16* __restrict__ A, const bf16* __restrict__ Bw,
    bf16* __restrict__ qOut, bf16* __restrict__ kOut, bf16* __restrict__ vOut)
{
    __shared__ bf16 As[BM * BK];
    __shared__ bf16 Bs[BN * BK];

    const int tid  = threadIdx.x;
    const int wave = tid >> 6;
    const int lane = tid & 63;
    const int quad = lane >> 4;
    const int l16  = lane & 15;
    const int wr   = wave >> 1;
    const int wc   = wave & 1;
    const int m0   = blockIdx.y * BM;
    const int o0   = blockIdx.x * BN;

    const int srow = lane >> 2;
    const int scol = (lane & 3) * 8;

    f32x4 acc[4][4] = {};

    for (int k0 = 0; k0 < CC; k0 += BK) {
        __syncthreads();
        #pragma unroll
        for (int c = 0; c < 2; ++c) {
            const int rbase = wave * 32 + c * 16;
            GLOAD_LDS(A + (size_t)(m0 + rbase + srow) * CC + k0 + scol, &As[rbase * BK]);
            GLOAD_LDS(Bw + (size_t)(o0 + rbase + srow) * CC + k0 + scol, &Bs[rbase * BK]);
        }
        __syncthreads();

        short8 af[4], bfr[4];
        #pragma unroll
        for (int i = 0; i < 4; ++i)
            af[i] = *(const short8*)&As[(wr * 64 + i * 16 + l16) * BK + quad * 8];
        #pragma unroll
        for (int j = 0; j < 4; ++j)
            bfr[j] = *(const short8*)&Bs[(wc * 64 + j * 16 + l16) * BK + quad * 8];
        #pragma unroll
        for (int i = 0; i < 4; ++i)
            #pragma unroll
            for (int j = 0; j < 4; ++j)
                acc[i][j] = MFMA16(af[i], bfr[j], acc[i][j]);
    }

    // epilogue: C/D layout col=l16, row=quad*4+reg
    if (o0 >= 2 * CC) {   // V block -> vPack[h][tile][kvchunk][d][8]
        #pragma unroll
        for (int j = 0; j < 4; ++j) {
            const int dcol = o0 - 2 * CC + wc * 64 + j * 16 + l16;
            const int hV = dcol >> 6, dV = dcol & 63;
            #pragma unroll
            for (int i = 0; i < 4; ++i) {
                const int kv0 = m0 + wr * 64 + i * 16 + quad * 4;
                const size_t addr = (size_t)hV * 64 * AN + (size_t)(kv0 >> 6) * 4096
                                  + (size_t)((kv0 >> 3) & 7) * 512 + dV * 8 + (kv0 & 7);
                *(short4v*)&vOut[addr] =
                    pack4(acc[i][j][0], acc[i][j][1], acc[i][j][2], acc[i][j][3]);
            }
        }
        return;
    }
    if (o0 >= CC) {       // K block -> kPack[h][tile][dchunk][row][8]
        #pragma unroll
        for (int j = 0; j < 4; ++j) {
            const int dcol = o0 - CC + wc * 64 + j * 16 + l16;
            const int hK = dcol >> 6, dc = (dcol >> 3) & 7, de = dcol & 7;
            #pragma unroll
            for (int i = 0; i < 4; ++i) {
                const int kv0 = m0 + wr * 64 + i * 16 + quad * 4;
                const size_t addr = (size_t)hK * 64 * AN + (size_t)(kv0 >> 6) * 4096
                                  + (size_t)dc * 512 + (size_t)(kv0 & 63) * 8 + de;
                #pragma unroll
                for (int r = 0; r < 4; ++r)
                    kOut[addr + r * 8] = sbf(bf16s(acc[i][j][r]));
            }
        }
        return;
    }
    // Q block -> qbuf[n][CC], scaled
    #pragma unroll
    for (int j = 0; j < 4; ++j) {
        const int col = o0 + wc * 64 + j * 16 + l16;
        #pragma unroll
        for (int i = 0; i < 4; ++i) {
            const int row = m0 + wr * 64 + i * 16 + quad * 4;
            #pragma unroll
            for (int r = 0; r < 2; ++r) {
                short2v p = pk2(acc[i][j][2 * r] * QSCALE, acc[i][j][2 * r + 1] * QSCALE);
                qOut[(size_t)(row + 2 * r) * CC + col]     = sbf(p[0]);
                qOut[(size_t)(row + 2 * r + 1) * CC + col] = sbf(p[1]);
            }
        }
    }
}

// ---------------------------------------------------------------------------
// Proj GEMM: out[m][o] = sum_c attn[m][c]*wp[o][c] + bias[o].
// 128x64 tile -> grid 16x32 = 512 = 2 blocks/CU exact fill.
// ---------------------------------------------------------------------------
constexpr int PM = 128, PN = 64, PK = 32;

__global__ __launch_bounds__(256, 2) void gemm_proj(
    const bf16* __restrict__ A, const bf16* __restrict__ Bw,
    const float* __restrict__ bias, void* __restrict__ Cout,
    const int* __restrict__ mode)
{
    __shared__ bf16 As[PM * PK];   // 8 KB
    __shared__ bf16 Bs[PN * PK];   // 4 KB

    const int tid  = threadIdx.x;
    const int wave = tid >> 6;
    const int lane = tid & 63;
    const int quad = lane >> 4;
    const int l16  = lane & 15;
    const int wr   = wave >> 1;
    const int wc   = wave & 1;
    const int m0   = blockIdx.y * PM;
    const int o0   = blockIdx.x * PN;
    const bool f32out = (*mode != 0);

    const int srow = lane >> 2;
    const int scol = (lane & 3) * 8;

    f32x4 acc[4][2] = {};

    for (int k0 = 0; k0 < CC; k0 += PK) {
        __syncthreads();
        #pragma unroll
        for (int c = 0; c < 2; ++c) {
            const int rbase = wave * 32 + c * 16;
            GLOAD_LDS(A + (size_t)(m0 + rbase + srow) * CC + k0 + scol, &As[rbase * PK]);
        }
        {
            const int rbase = wave * 16;
            GLOAD_LDS(Bw + (size_t)(o0 + rbase + srow) * CC + k0 + scol, &Bs[rbase * PK]);
        }
        __syncthreads();

        short8 af[4], bfr[2];
        #pragma unroll
        for (int i = 0; i < 4; ++i)
            af[i] = *(const short8*)&As[(wr * 64 + i * 16 + l16) * PK + quad * 8];
        #pragma unroll
        for (int j = 0; j < 2; ++j)
            bfr[j] = *(const short8*)&Bs[(wc * 32 + j * 16 + l16) * PK + quad * 8];
        #pragma unroll
        for (int i = 0; i < 4; ++i)
            #pragma unroll
            for (int j = 0; j < 2; ++j)
                acc[i][j] = MFMA16(af[i], bfr[j], acc[i][j]);
    }

    #pragma unroll
    for (int j = 0; j < 2; ++j) {
        const int col = o0 + wc * 32 + j * 16 + l16;
        const float bv = bias[col];
        #pragma unroll
        for (int i = 0; i < 4; ++i) {
            const int row = m0 + wr * 64 + i * 16 + quad * 4;
            if (f32out) {
                #pragma unroll
                for (int r = 0; r < 4; ++r)
                    ((float*)Cout)[(size_t)(row + r) * CC + col] = acc[i][j][r] + bv;
            } else {
                #pragma unroll
                for (int r = 0; r < 2; ++r) {
                    short2v p = pk2(acc[i][j][2 * r] + bv, acc[i][j][2 * r + 1] + bv);
                    ((bf16*)Cout)[(size_t)(row + 2 * r) * CC + col]     = sbf(p[0]);
                    ((bf16*)Cout)[(size_t)(row + 2 * r + 1) * CC + col] = sbf(p[1]);
                }
            }
        }
    }
}

// ---------------------------------------------------------------------------
// Causal flash attention v18: attn14's winning program (56.4 us) with ONE
// change — XCD-head-affinity block decomposition.
// Theory: per-iter wall (~2150 cy) exceeds issue+dep (~1000 cy) because V
// loads (issued at iter top, consumed ~500 cy later after S+softmax) miss
// the per-XCD L2: with h = bid&15, every XCD's 4 MB L2 sees all 16 heads'
// K/V (16 MB) -> L3 latency (~600+ cy) lands on the critical path.
// Fix: h = ((bid&7)<<1)|((bid>>3)&1) so (assuming HW round-robin
// xcd = bid%8) XCD x serves only heads {2x,2x+1} = 2 MB <= 4 MB L2.
// If the mapping assumption is wrong this is a harmless permutation.
//  - 512 blocks, 4 waves = (rowhalf rh, kv-half s); pp phases (bp, 63-bp);
//    in-block combine via LDS (s=1 parks, s=0 merges+writes); per-wave
//    inner program byte-identical to attn8/14.
// ---------------------------------------------------------------------------
__global__ __launch_bounds__(256, 2) void attn18(
    const bf16* __restrict__ qbuf, const bf16* __restrict__ kP,
    const bf16* __restrict__ vP, bf16* __restrict__ outO)
{
    __shared__ float ldsO[2][32][64];   // [rh][reg][lane] 16 KB
    __shared__ float ldsL[2][64];       // 512 B

    const int tid  = threadIdx.x;
    const int w    = tid >> 6;        // 0..3
    const int rh   = w & 1;           // q row-half
    const int s    = w >> 1;          // kv half
    const int lane = tid & 63;
    const int l31  = lane & 31;
    const int hh   = lane >> 5;       // K-half of the 32x32x16 fragment
    const int bid  = blockIdx.x;
    // XCD-head affinity: xcd = bid%8 (assumed round-robin) -> heads {2x,2x+1}
    const int h    = ((bid & 7) << 1) | ((bid >> 3) & 1);
    const int bp   = bid >> 4;        // 0..31

    short8 ones8;
    #pragma unroll
    for (int i = 0; i < 8; ++i) ones8[i] = (short)0x3F80;

    #pragma unroll 1
    for (int pp = 0; pp < 2; ++pp) {
        const int tile = pp ? 63 - bp : bp;
        const int nIt  = tile + 1;
        const int mid  = (nIt + 1) >> 1;
        const int i0   = s ? mid : 0;
        const int iHi  = s ? nIt : mid;
        const int qw   = tile * 64 + rh * 32;
        const int q    = qw + l31;

        // Q fragments: B-operand Q[k=hd][col=q]; hd = ki*16 + hh*8 + j
        short8 qf[4];
        {
            const bf16* qp = qbuf + (size_t)q * CC + h * HD + hh * 8;
            #pragma unroll
            for (int ki = 0; ki < 4; ++ki)
                qf[ki] = *(const short8*)(qp + ki * 16);
        }

        f32x16 acc_l = {};       // lsum (rows identical per lane)
        f32x16 acc_o[2] = {};    // O^T: row d = dt*32 + (r&3)+8*(r>>2)+4*hh, col q=l31

        if (i0 < iHi) {
            const bf16* kb = kP + (size_t)h * 64 * AN + (size_t)i0 * 4096;
            const bf16* vb = vP + (size_t)h * 64 * AN + (size_t)i0 * 4096;
            const bool hasdiag = (iHi == nIt);

            // prologue: K(i0) direct to registers
            short8 kf[8];
            #pragma unroll
            for (int kt = 0; kt < 2; ++kt)
                #pragma unroll
                for (int ki = 0; ki < 4; ++ki)
                    kf[kt * 4 + ki] = *(const short8*)
                        (kb + (2 * ki + hh) * 512 + kt * 256 + l31 * 8);
            kb += 4096;

            for (int it = i0; it < iHi; ++it) {
                // ---- issue V(it) loads (consumed in PV, after S+softmax) ----
                short8 vf[8];
                #pragma unroll
                for (int kk = 0; kk < 4; ++kk)
                    #pragma unroll
                    for (int dt2 = 0; dt2 < 2; ++dt2)
                        vf[kk * 2 + dt2] = *(const short8*)
                            (vb + (2 * kk + hh) * 512 + dt2 * 256 + l31 * 8);
                vb += 4096;

                // ---- S^T = K.Q^T, two 32x32 kv-subtiles ----
                f32x16 st[2];
                __builtin_amdgcn_s_setprio(1);
                #pragma unroll
                for (int kt = 0; kt < 2; ++kt) {
                    f32x16 a = {};
                    #pragma unroll
                    for (int ki = 0; ki < 4; ++ki)
                        a = MFMA32(kf[kt * 4 + ki], qf[ki], a);
                    st[kt] = a;
                }
                __builtin_amdgcn_s_setprio(0);

                // ---- issue K(it+1) into kf (regs dead after S) ----
                if (it + 1 < iHi) {
                    #pragma unroll
                    for (int kt = 0; kt < 2; ++kt)
                        #pragma unroll
                        for (int ki = 0; ki < 4; ++ki)
                            kf[kt * 4 + ki] = *(const short8*)
                                (kb + (2 * ki + hh) * 512 + kt * 256 + l31 * 8);
                    kb += 4096;
                }

                // ---- fixed-max softmax: P = exp2(s), mask on diag tile ----
                if (hasdiag && it == iHi - 1) {
                    const int kv0 = it * 64;
                    #pragma unroll
                    for (int kt = 0; kt < 2; ++kt)
                        #pragma unroll
                        for (int r = 0; r < 16; ++r) {
                            const int kv = kv0 + kt * 32 + (r & 3) + 8 * (r >> 2) + 4 * hh;
                            st[kt][r] = (kv <= q) ? FAST_EXP2(st[kt][r]) : 0.0f;
                        }
                } else {
                    #pragma unroll
                    for (int kt = 0; kt < 2; ++kt)
                        #pragma unroll
                        for (int r = 0; r < 16; ++r)
                            st[kt][r] = FAST_EXP2(st[kt][r]);
                }

                // ---- P B-frags (cvt_pk + permlane32_swap), lsum-MFMA + PV ----
                #pragma unroll
                for (int kt = 0; kt < 2; ++kt)
                    #pragma unroll
                    for (int kc = 0; kc < 2; ++kc) {
                        unsigned a0 = pk2u(st[kt][kc * 8 + 0], st[kt][kc * 8 + 1]);
                        unsigned a1 = pk2u(st[kt][kc * 8 + 2], st[kt][kc * 8 + 3]);
                        unsigned c0 = pk2u(st[kt][kc * 8 + 4], st[kt][kc * 8 + 5]);
                        unsigned c1 = pk2u(st[kt][kc * 8 + 6], st[kt][kc * 8 + 7]);
                        plswap(a0, c0);
                        plswap(a1, c1);
                        uintv4 fu;
                        fu[0] = a0; fu[1] = a1; fu[2] = c0; fu[3] = c1;
                        const short8 frag = *(const short8*)&fu;

                        __builtin_amdgcn_s_setprio(1);
                        acc_l = MFMA32(ones8, frag, acc_l);
                        #pragma unroll
                        for (int dt2 = 0; dt2 < 2; ++dt2)
                            acc_o[dt2] = MFMA32(vf[(kt * 2 + kc) * 2 + dt2],
                                                frag, acc_o[dt2]);
                        __builtin_amdgcn_s_setprio(0);
                    }
            }
        }

        // ---- in-block combine: s=1 parks partials, s=0 merges & writes ----
        if (s == 1) {
            #pragma unroll
            for (int dt2 = 0; dt2 < 2; ++dt2)
                #pragma unroll
                for (int r = 0; r < 16; ++r)
                    ldsO[rh][dt2 * 16 + r][lane] = acc_o[dt2][r];
            ldsL[rh][lane] = acc_l[0];
        }
        __syncthreads();
        if (s == 0) {
            const float L = acc_l[0] + ldsL[rh][lane];
            const float invL = (L > 0.f) ? 1.f / L : 0.f;
            const size_t base = (size_t)q * CC + h * HD;
            #pragma unroll
            for (int dt2 = 0; dt2 < 2; ++dt2)
                #pragma unroll
                for (int g = 0; g < 4; ++g) {
                    const int d0 = dt2 * 32 + g * 8 + 4 * hh;
                    float o0 = (acc_o[dt2][4 * g + 0] + ldsO[rh][dt2 * 16 + 4 * g + 0][lane]) * invL;
                    float o1 = (acc_o[dt2][4 * g + 1] + ldsO[rh][dt2 * 16 + 4 * g + 1][lane]) * invL;
                    float o2 = (acc_o[dt2][4 * g + 2] + ldsO[rh][dt2 * 16 + 4 * g + 2][lane]) * invL;
                    float o3 = (acc_o[dt2][4 * g + 3] + ldsO[rh][dt2 * 16 + 4 * g + 3][lane]) * invL;
                    *(short4v*)&outO[base + d0] = pack4(o0, o1, o2, o3);
                }
        }
        __syncthreads();   // protect LDS reuse in next phase
    }
}

// ---------------------------------------------------------------------------
extern "C" void kernel_launch(void* const* d_in, const int* in_sizes, int n_in,
                              void* d_out, int out_size, void* d_ws, size_t ws_size,
                              hipStream_t stream) {
    char* ws = (char*)d_ws;
    bf16*   qbuf     = (bf16*)(ws);                    //  8 MiB [4096][1024]
    bf16*   kPack    = (bf16*)(ws + 8388608);          //  8 MiB frag-major K
    bf16*   vPack    = (bf16*)(ws + 16777216);         //  8 MiB frag-major V
    bf16*   attn_out = (bf16*)(ws + 25165824);         //  8 MiB [4096][1024]
    bf16*   xb       = (bf16*)(ws + 33554432);         //  8 MiB
    bf16*   wqkvb    = (bf16*)(ws + 41943040);         //  6 MiB
    bf16*   wprojb   = (bf16*)(ws + 48234496);         //  2 MiB
    float*  biasf    = (float*)(ws + 50331648);        //  4 KiB
    int*    mode     = (int*)(ws + 50335744);

    cast_all<<<dim3(4097), 256, 0, stream>>>(
        d_in[0], d_in[1], d_in[2], d_in[3], xb, wqkvb, wprojb, biasf, mode);

    // QKV projection: Q scaled -> qbuf; K -> kPack; V -> vPack (frag-major)
    gemm_qkv<<<dim3(C3 / BN, AN / BM), 256, 0, stream>>>(
        xb, wqkvb, qbuf, kPack, vPack);
    // causal flash attention: XCD-head affinity, in-block kv-split combine
    attn18<<<dim3(32 * NH), 256, 0, stream>>>(qbuf, kPack, vPack, attn_out);
    // output projection + bias
    gemm_proj<<<dim3(CC / PN, AN / PM), 256, 0, stream>>>(
        attn_out, wprojb, biasf, d_out, mode);
}